// Round 2
// baseline (379.822 us; speedup 1.0000x reference)
//
#include <hip/hip_runtime.h>

#define T_DIM 60
#define M_DIM 8

__global__ void init_kernel(float* __restrict__ ws_npred, float* __restrict__ out) {
    int i = threadIdx.x;
    if (i < T_DIM) ws_npred[i] = 0.0f;
    if (i == 0) out[0] = 0.0f;
}

// n_pred[t] = sum_n mask[n,t]; coalesced grid-stride read, LDS bins, few atomics.
__global__ void npred_kernel(const float* __restrict__ mask,
                             float* __restrict__ ws_npred, int NT) {
    __shared__ float bins[T_DIM];
    for (int j = threadIdx.x; j < T_DIM; j += blockDim.x) bins[j] = 0.0f;
    __syncthreads();
    int stride = gridDim.x * blockDim.x;
    for (int i = blockIdx.x * blockDim.x + threadIdx.x; i < NT; i += stride) {
        int t = i % T_DIM;
        atomicAdd(&bins[t], mask[i]);
    }
    __syncthreads();
    for (int j = threadIdx.x; j < T_DIM; j += blockDim.x)
        atomicAdd(&ws_npred[j], bins[j]);
}

// Quad-cooperative: 4 lanes per (n,t) element. Lane l owns mixture components
// {l, l+4}. All vector loads are wave-coalesced:
//   sigma: lane reads float4 #l and #(l+4) of the element's 8 -> per
//          instruction the wave reads 64 consecutive float4s (full lines).
//   mu:    lane reads float2 #l and #(l+4) of the element's 8.
// LSE over the 8 components = local pair + shfl_xor(1) + shfl_xor(2).
__global__ __launch_bounds__(256)
void loss_kernel(const float* __restrict__ mu,
                 const float* __restrict__ sigma,
                 const float* __restrict__ pi,
                 const float* __restrict__ x,
                 const float* __restrict__ mask,
                 const float* __restrict__ ws_npred,
                 float* __restrict__ out, int NT) {
    const float LOG_2PI = 1.8378770664093453f;
    int tid = threadIdx.x;
    int l = tid & 3;                       // lane within quad
    int gid = blockIdx.x * 64 + (tid >> 2); // element index i = n*T + t
    float contrib = 0.0f;

    if (gid < NT) {
        int n = gid / T_DIM;
        int t = gid - n * T_DIM;

        // small scalars (broadcast within quad; L1 serves duplicates)
        float2 xv = ((const float2*)x)[gid];
        float mk = mask[gid];
        float npr = ws_npred[t];

        // mu: element base gid*16 floats; lane grabs components l and l+4
        const float2* mu2 = (const float2*)(mu + (size_t)gid * 16);
        float2 m_lo = mu2[l];
        float2 m_hi = mu2[l + 4];

        // sigma: element base gid*32 floats = 8 float4; lane grabs #l, #(l+4)
        const float4* sg4 = (const float4*)(sigma + (size_t)gid * 32);
        float4 s_lo = sg4[l];
        float4 s_hi = sg4[l + 4];

        // pi logits for this lane's two components
        const float* pib = pi + (size_t)n * 8;
        float p_lo = pib[l];
        float p_hi = pib[l + 4];

        // component log-probs (closed-form 2x2)
        float lp0, lp1;
        {
            float a = s_lo.x, b = s_lo.y, c = s_lo.w;
            float d1 = xv.x - m_lo.x, d2 = xv.y - m_lo.y;
            float det = a * c - b * b;
            float maha = (c * d1 * d1 - 2.0f * b * d1 * d2 + a * d2 * d2) / det;
            lp0 = p_lo - LOG_2PI - 0.5f * (maha + __logf(det));
        }
        {
            float a = s_hi.x, b = s_hi.y, c = s_hi.w;
            float d1 = xv.x - m_hi.x, d2 = xv.y - m_hi.y;
            float det = a * c - b * b;
            float maha = (c * d1 * d1 - 2.0f * b * d1 * d2 + a * d2 * d2) / det;
            lp1 = p_hi - LOG_2PI - 0.5f * (maha + __logf(det));
        }

        // LSE over 8 components across the quad
        float mx = fmaxf(lp0, lp1);
        mx = fmaxf(mx, __shfl_xor(mx, 1));
        mx = fmaxf(mx, __shfl_xor(mx, 2));
        float s = __expf(lp0 - mx) + __expf(lp1 - mx);
        s += __shfl_xor(s, 1);
        s += __shfl_xor(s, 2);
        float lse_num = mx + __logf(s);

        // LSE over pi logits (normalizer)
        float pmx = fmaxf(p_lo, p_hi);
        pmx = fmaxf(pmx, __shfl_xor(pmx, 1));
        pmx = fmaxf(pmx, __shfl_xor(pmx, 2));
        float ps = __expf(p_lo - pmx) + __expf(p_hi - pmx);
        ps += __shfl_xor(ps, 1);
        ps += __shfl_xor(ps, 2);
        float lse_pi = pmx + __logf(ps);

        float loss = lse_pi - lse_num;           // = -gmm_lp
        float v = loss * mk / npr;
        contrib = (l == 0) ? v : 0.0f;           // one lane per element contributes
    }

    // wave (64) shuffle reduce -> LDS -> one atomic per block
#pragma unroll
    for (int off = 32; off > 0; off >>= 1)
        contrib += __shfl_down(contrib, off);
    __shared__ float wsum[4];
    int lane = tid & 63;
    int wid = tid >> 6;
    if (lane == 0) wsum[wid] = contrib;
    __syncthreads();
    if (tid == 0) {
        float v = wsum[0] + wsum[1] + wsum[2] + wsum[3];
        atomicAdd(out, v);
    }
}

extern "C" void kernel_launch(void* const* d_in, const int* in_sizes, int n_in,
                              void* d_out, int out_size, void* d_ws, size_t ws_size,
                              hipStream_t stream) {
    const float* mu    = (const float*)d_in[0];   // (N,T,M,K)
    const float* sigma = (const float*)d_in[1];   // (N,T,M,K,K)
    const float* pi    = (const float*)d_in[2];   // (N,M)
    const float* x     = (const float*)d_in[3];   // (N,T,K)
    const float* mask  = (const float*)d_in[4];   // (N,T)
    float* out = (float*)d_out;
    float* ws_npred = (float*)d_ws;               // 60 floats

    int NT = in_sizes[4];                          // N*T = 983040

    hipLaunchKernelGGL(init_kernel, dim3(1), dim3(64), 0, stream, ws_npred, out);
    hipLaunchKernelGGL(npred_kernel, dim3(240), dim3(256), 0, stream,
                       mask, ws_npred, NT);
    // 64 elements per 256-thread block (4 lanes/element)
    hipLaunchKernelGGL(loss_kernel, dim3((NT + 63) / 64), dim3(256), 0, stream,
                       mu, sigma, pi, x, mask, ws_npred, out, NT);
}

// Round 3
// 248.250 us; speedup vs baseline: 1.5300x; 1.5300x over previous
//
#include <hip/hip_runtime.h>

#define T_DIM 60
#define M_DIM 8
#define LOSS_BLOCKS 3840          // NT / 256 exactly (983040 = 3840*256)
#define PARTIALS_OFF 64           // float offset into ws: [0..59]=npred, [64..]=partials

__global__ void init_kernel(float* __restrict__ ws_npred) {
    int i = threadIdx.x;
    if (i < T_DIM) ws_npred[i] = 0.0f;
}

// n_pred[t] = sum_n mask[n,t]; coalesced grid-stride read, LDS bins.
// Global atomics: 60 distinct addresses x 240 blocks -> per-address chains of
// 240 only (different-address RMWs pipeline) — not the same-address convoy.
__global__ void npred_kernel(const float* __restrict__ mask,
                             float* __restrict__ ws_npred, int NT) {
    __shared__ float bins[T_DIM];
    for (int j = threadIdx.x; j < T_DIM; j += blockDim.x) bins[j] = 0.0f;
    __syncthreads();
    int stride = gridDim.x * blockDim.x;
    for (int i = blockIdx.x * blockDim.x + threadIdx.x; i < NT; i += stride) {
        int t = i % T_DIM;
        atomicAdd(&bins[t], mask[i]);
    }
    __syncthreads();
    for (int j = threadIdx.x; j < T_DIM; j += blockDim.x)
        atomicAdd(&ws_npred[j], bins[j]);
}

// One thread per (n,t). Closed-form 2x2 Cholesky equivalents:
// det = ac - b^2, maha = (c d1^2 - 2b d1 d2 + a d2^2)/det, log|L| = 0.5 log det.
// NO global atomic here: block partial -> plain store to ws_partials[blockIdx].
// (Round-2 lesson: same-address atomicAdd serializes ~30cy/block at the TCC —
//  WRITE_SIZE showed exactly 32B x #blocks of RMW write-backs.)
__global__ __launch_bounds__(256)
void loss_kernel(const float* __restrict__ mu,
                 const float* __restrict__ sigma,
                 const float* __restrict__ pi,
                 const float* __restrict__ x,
                 const float* __restrict__ mask,
                 const float* __restrict__ ws_npred,
                 float* __restrict__ ws_partials, int NT) {
    const float LOG_2PI = 1.8378770664093453f;
    int i = blockIdx.x * blockDim.x + threadIdx.x;
    float contrib = 0.0f;
    if (i < NT) {
        int n = i / T_DIM;
        int t = i - n * T_DIM;

        float2 xv = ((const float2*)x)[i];
        float mk = mask[i];

        const float4* mu4 = (const float4*)(mu + (size_t)i * 16);
        float4 mv0 = mu4[0], mv1 = mu4[1], mv2 = mu4[2], mv3 = mu4[3];
        const float4* sg4 = (const float4*)(sigma + (size_t)i * 32);
        float4 sg[M_DIM];
#pragma unroll
        for (int m = 0; m < M_DIM; ++m) sg[m] = sg4[m];
        const float4* pi4 = (const float4*)(pi + (size_t)n * 8);
        float4 p0 = pi4[0], p1 = pi4[1];

        float mus[2 * M_DIM] = {mv0.x, mv0.y, mv0.z, mv0.w,
                                mv1.x, mv1.y, mv1.z, mv1.w,
                                mv2.x, mv2.y, mv2.z, mv2.w,
                                mv3.x, mv3.y, mv3.z, mv3.w};
        float pis[M_DIM] = {p0.x, p0.y, p0.z, p0.w, p1.x, p1.y, p1.z, p1.w};

        float lp[M_DIM];
#pragma unroll
        for (int m = 0; m < M_DIM; ++m) {
            float a = sg[m].x, b = sg[m].y, c = sg[m].w;
            float d1 = xv.x - mus[2 * m];
            float d2 = xv.y - mus[2 * m + 1];
            float det = a * c - b * b;        // SPD: det >= 0.25 by construction
            float maha = (c * d1 * d1 - 2.0f * b * d1 * d2 + a * d2 * d2) / det;
            float mvn = -LOG_2PI - 0.5f * (maha + __logf(det));
            lp[m] = pis[m] + mvn;
        }

        float mx = lp[0];
#pragma unroll
        for (int m = 1; m < M_DIM; ++m) mx = fmaxf(mx, lp[m]);
        float s = 0.0f;
#pragma unroll
        for (int m = 0; m < M_DIM; ++m) s += __expf(lp[m] - mx);
        float lse_num = mx + __logf(s);

        float pmx = pis[0];
#pragma unroll
        for (int m = 1; m < M_DIM; ++m) pmx = fmaxf(pmx, pis[m]);
        float ps = 0.0f;
#pragma unroll
        for (int m = 0; m < M_DIM; ++m) ps += __expf(pis[m] - pmx);
        float lse_pi = pmx + __logf(ps);

        float loss = lse_pi - lse_num;        // = -gmm_lp
        contrib = loss * mk / ws_npred[t];
    }

    // wave (64) shuffle reduce -> LDS -> ONE PLAIN STORE per block (no atomic)
#pragma unroll
    for (int off = 32; off > 0; off >>= 1)
        contrib += __shfl_down(contrib, off);
    __shared__ float wsum[4];
    int lane = threadIdx.x & 63;
    int wid = threadIdx.x >> 6;
    if (lane == 0) wsum[wid] = contrib;
    __syncthreads();
    if (threadIdx.x == 0)
        ws_partials[blockIdx.x] = wsum[0] + wsum[1] + wsum[2] + wsum[3];
}

// Single block sums the 3840 block partials into out[0].
__global__ void finalize_kernel(const float* __restrict__ ws_partials,
                                float* __restrict__ out, int nblocks) {
    float s = 0.0f;
    for (int i = threadIdx.x; i < nblocks; i += blockDim.x)
        s += ws_partials[i];
#pragma unroll
    for (int off = 32; off > 0; off >>= 1)
        s += __shfl_down(s, off);
    __shared__ float wsum[4];
    int lane = threadIdx.x & 63;
    int wid = threadIdx.x >> 6;
    if (lane == 0) wsum[wid] = s;
    __syncthreads();
    if (threadIdx.x == 0)
        out[0] = wsum[0] + wsum[1] + wsum[2] + wsum[3];
}

extern "C" void kernel_launch(void* const* d_in, const int* in_sizes, int n_in,
                              void* d_out, int out_size, void* d_ws, size_t ws_size,
                              hipStream_t stream) {
    const float* mu    = (const float*)d_in[0];   // (N,T,M,K)
    const float* sigma = (const float*)d_in[1];   // (N,T,M,K,K)
    const float* pi    = (const float*)d_in[2];   // (N,M)
    const float* x     = (const float*)d_in[3];   // (N,T,K)
    const float* mask  = (const float*)d_in[4];   // (N,T)
    float* out = (float*)d_out;
    float* ws_npred    = (float*)d_ws;                 // 60 floats
    float* ws_partials = (float*)d_ws + PARTIALS_OFF;  // 3840 floats

    int NT = in_sizes[4];                          // N*T = 983040

    hipLaunchKernelGGL(init_kernel, dim3(1), dim3(64), 0, stream, ws_npred);
    hipLaunchKernelGGL(npred_kernel, dim3(240), dim3(256), 0, stream,
                       mask, ws_npred, NT);
    hipLaunchKernelGGL(loss_kernel, dim3(LOSS_BLOCKS), dim3(256), 0, stream,
                       mu, sigma, pi, x, mask, ws_npred, ws_partials, NT);
    hipLaunchKernelGGL(finalize_kernel, dim3(1), dim3(256), 0, stream,
                       ws_partials, out, LOSS_BLOCKS);
}